// Round 1
// baseline (5559.915 us; speedup 1.0000x reference)
//
#include <hip/hip_runtime.h>

// ---------------------------------------------------------------------------
// BaselineLSTM: embed -> 2-layer LSTM(H=256) -> LN -> 9-head proj -> outputs
// B=128, S=1024, H=256, D_IN=84, NPHN=40, DEPTH=2, N_HEADS=9
// ---------------------------------------------------------------------------

typedef _Float16 h2    __attribute__((ext_vector_type(2)));
typedef _Float16 f16x8 __attribute__((ext_vector_type(8)));
typedef float    f32x4 __attribute__((ext_vector_type(4)));

#define NW_MAT 262144   // 1024*256 elements per weight matrix

static __device__ __forceinline__ float fdot2u(unsigned int w, unsigned int h, float c){
#if defined(__has_builtin) && __has_builtin(__builtin_amdgcn_fdot2)
  return __builtin_amdgcn_fdot2(__builtin_bit_cast(h2, w), __builtin_bit_cast(h2, h), c, false);
#else
  h2 a = __builtin_bit_cast(h2, w), b = __builtin_bit_cast(h2, h);
  return c + (float)a[0]*(float)b[0] + (float)a[1]*(float)b[1];
#endif
}
static __device__ __forceinline__ float sigmf(float x){ return 1.f/(1.f + __expf(-x)); }
static __device__ __forceinline__ float tanhf_(float x){ return 1.f - 2.f/(__expf(2.f*x) + 1.f); }

// --------------------------- prep: f32->f16 weights, fused bias/score vecs --
__global__ void k_prep(const float* __restrict__ w_ih, const float* __restrict__ w_hh,
                       const float* __restrict__ b_ih, const float* __restrict__ b_hh,
                       const float* __restrict__ ln_g, const float* __restrict__ ln_b,
                       const float* __restrict__ head_w, const float* __restrict__ head_b,
                       _Float16* wih0, _Float16* whh0, _Float16* wih1, _Float16* whh1,
                       float* bias0, float* bias1, float* vk, float* ck)
{
  int i = blockIdx.x*256 + threadIdx.x;
  if (i < NW_MAT){
    wih0[i] = (_Float16)w_ih[i];
    whh0[i] = (_Float16)w_hh[i];
    wih1[i] = (_Float16)w_ih[NW_MAT + i];
    whh1[i] = (_Float16)w_hh[NW_MAT + i];
  }
  if (i < 1024){
    bias0[i] = b_ih[i]        + b_hh[i];
    bias1[i] = b_ih[1024 + i] + b_hh[1024 + i];
  }
  if (i < 2304) vk[i] = ln_g[i]*head_w[i];
  if (i < 9){
    float s = 0.f;
    for (int h = 0; h < 256; ++h) s += ln_b[i*256 + h]*head_w[i*256 + h];
    ck[i] = s + head_b[i];
  }
}

// --------------------------- idx[b] = last valid position ------------------
__global__ void k_idx(const int* __restrict__ phn, int* __restrict__ idx)
{
  int b = blockIdx.x, l = threadIdx.x;
  int found = -1;
  for (int t0 = 0; t0 < 1024; t0 += 64){
    int v = phn[b*1024 + t0 + l];
    unsigned long long m = __ballot(v < 0);
    if (m){ found = t0 + (__ffsll(m) - 1); break; }
  }
  if (l == 0) idx[b] = (found < 0) ? 1023 : found - 1;
}

// --------------------------- embed: E = x@Win^T + b + phn lookup (f16) -----
__global__ void k_embed(const float* __restrict__ x, const int* __restrict__ phn,
                        const float* __restrict__ ipw, const float* __restrict__ ipb,
                        const float* __restrict__ ppw, const float* __restrict__ ppb,
                        _Float16* __restrict__ E, int Tc, int LT, int tc0)
{
  __shared__ float xs[8][84];
  __shared__ int pv[8];
  int tid = threadIdx.x;
  int m0 = blockIdx.x * 8;
  for (int i = tid; i < 8*84; i += 256){
    int r = i/84, k = i - r*84;
    int m = m0 + r; int b = m >> LT; int t = tc0 + (m & (Tc-1));
    xs[r][k] = x[((size_t)b*1024 + t)*84 + k];
  }
  if (tid < 8){
    int m = m0 + tid; int b = m >> LT; int t = tc0 + (m & (Tc-1));
    pv[tid] = phn[b*1024 + t];
  }
  __syncthreads();
  float acc[8] = {0.f,0.f,0.f,0.f,0.f,0.f,0.f,0.f};
  const float* wrow = ipw + tid*84;
  for (int k = 0; k < 84; ++k){
    float wv = wrow[k];
    #pragma unroll
    for (int r = 0; r < 8; ++r) acc[r] += wv * xs[r][k];
  }
  float base = ipb[tid] + ppb[tid];
  #pragma unroll
  for (int r = 0; r < 8; ++r){
    float e = acc[r] + base + ppw[tid*40 + (pv[r] + 1)];
    E[(size_t)(m0 + r)*256 + tid] = (_Float16)e;
  }
}

// --------------------------- GEMM: C[M][1024] = A[M][256] @ W[1024][256]^T + bias
__global__ __launch_bounds__(256) void k_gemm(const _Float16* __restrict__ A,
                                              const _Float16* __restrict__ Bw,
                                              const float* __restrict__ bias,
                                              _Float16* __restrict__ C)
{
  __shared__ __align__(16) _Float16 lA[128*64];
  __shared__ __align__(16) _Float16 lB[128*64];
  int tid = threadIdx.x;
  int tm = blockIdx.x, tn = blockIdx.y;
  int l = tid & 63, w = tid >> 6;
  int wm = w >> 1, wn = w & 1;
  f32x4 acc[4][4];
  #pragma unroll
  for (int mi = 0; mi < 4; ++mi)
    #pragma unroll
    for (int ni = 0; ni < 4; ++ni) acc[mi][ni] = (f32x4){0.f,0.f,0.f,0.f};
  int rr = tid >> 3, cc = tid & 7;
  #pragma unroll 1
  for (int kb = 0; kb < 4; ++kb){
    uint4 av[4], bv[4];
    #pragma unroll
    for (int i = 0; i < 4; ++i){
      int r = rr + 32*i;
      av[i] = *(const uint4*)(A  + ((size_t)(tm*128 + r))*256 + kb*64 + cc*8);
      bv[i] = *(const uint4*)(Bw + ((size_t)(tn*128 + r))*256 + kb*64 + cc*8);
    }
    __syncthreads();
    #pragma unroll
    for (int i = 0; i < 4; ++i){
      int r = rr + 32*i;
      *(uint4*)&lA[r*64 + cc*8] = av[i];
      *(uint4*)&lB[r*64 + cc*8] = bv[i];
    }
    __syncthreads();
    #pragma unroll
    for (int kk = 0; kk < 2; ++kk){
      f16x8 aF[4], bF[4];
      #pragma unroll
      for (int mi = 0; mi < 4; ++mi)
        aF[mi] = *(const f16x8*)&lA[(wm*64 + mi*16 + (l&15))*64 + kk*32 + (l>>4)*8];
      #pragma unroll
      for (int ni = 0; ni < 4; ++ni)
        bF[ni] = *(const f16x8*)&lB[(wn*64 + ni*16 + (l&15))*64 + kk*32 + (l>>4)*8];
      #pragma unroll
      for (int mi = 0; mi < 4; ++mi)
        #pragma unroll
        for (int ni = 0; ni < 4; ++ni)
          acc[mi][ni] = __builtin_amdgcn_mfma_f32_16x16x32_f16(aF[mi], bF[ni], acc[mi][ni], 0, 0, 0);
    }
  }
  #pragma unroll
  for (int mi = 0; mi < 4; ++mi){
    #pragma unroll
    for (int ni = 0; ni < 4; ++ni){
      int n = tn*128 + wn*64 + ni*16 + (l & 15);
      float bn = bias[n];
      #pragma unroll
      for (int j = 0; j < 4; ++j){
        int m = tm*128 + wm*64 + mi*16 + (l>>4)*4 + j;
        C[(size_t)m*1024 + n] = (_Float16)(acc[mi][ni][j] + bn);
      }
    }
  }
}

// --------------------------- LSTM recurrence (one WG per batch chain) ------
// gates = G[t] (precomputed x-proj + bias) + Whh @ h.  512 thr, 2 rows each.
// Whh row split: elems 0..191 in VGPRs, 192..255 in LDS (XOR-swizzled).
__global__ __launch_bounds__(512, 2) void k_lstm(const _Float16* __restrict__ G,
                                                 const _Float16* __restrict__ W,
                                                 _Float16* __restrict__ Hout,
                                                 float* __restrict__ h_state,
                                                 float* __restrict__ c_state,
                                                 int Tc, int first)
{
  __shared__ __align__(16) unsigned int h_pk_s[128];   // h as 128 f16-pairs
  __shared__ float gf[1024];
  __shared__ __align__(16) unsigned int wlds[32768];   // 128 KB weight tail
  int tid = threadIdx.x;
  int b = blockIdx.x;
  int r0 = 2*tid, r1 = r0 + 1;
  const uint4* w0s = (const uint4*)(W + (size_t)r0*256);
  const uint4* w1s = (const uint4*)(W + (size_t)r1*256);
  uint4 w0v[24], w1v[24];
  #pragma unroll
  for (int c2 = 0; c2 < 24; ++c2){ w0v[c2] = w0s[c2]; w1v[c2] = w1s[c2]; }
  unsigned int swz = (unsigned int)(tid & 7);
  #pragma unroll
  for (int c2 = 0; c2 < 8; ++c2){
    *(uint4*)&wlds[tid*64      + (((unsigned)c2 ^ swz)*4)] = w0s[24 + c2];
    *(uint4*)&wlds[tid*64 + 32 + (((unsigned)c2 ^ swz)*4)] = w1s[24 + c2];
  }
  float c_reg = 0.f, hn = 0.f;
  if (tid < 256){
    float hv = 0.f;
    if (!first){ hv = h_state[b*256 + tid]; c_reg = c_state[b*256 + tid]; }
    ((_Float16*)h_pk_s)[tid] = (_Float16)hv;
    hn = hv;
  }
  __syncthreads();
  const unsigned int* gbase = (const unsigned int*)G + (size_t)b*Tc*512 + tid;
  _Float16* hout = Hout + (size_t)b*Tc*256;
  unsigned int gc = gbase[0];
  for (int tl = 0; tl < Tc; ++tl){
    unsigned int gn = (tl + 1 < Tc) ? gbase[(size_t)(tl + 1)*512] : 0u;
    const uint4* hp = (const uint4*)h_pk_s;
    float acc0 = 0.f, acc1 = 0.f;
    #pragma unroll
    for (int c2 = 0; c2 < 24; ++c2){
      uint4 h4 = hp[c2];
      acc0 = fdot2u(w0v[c2].x, h4.x, acc0);
      acc0 = fdot2u(w0v[c2].y, h4.y, acc0);
      acc0 = fdot2u(w0v[c2].z, h4.z, acc0);
      acc0 = fdot2u(w0v[c2].w, h4.w, acc0);
      acc1 = fdot2u(w1v[c2].x, h4.x, acc1);
      acc1 = fdot2u(w1v[c2].y, h4.y, acc1);
      acc1 = fdot2u(w1v[c2].z, h4.z, acc1);
      acc1 = fdot2u(w1v[c2].w, h4.w, acc1);
    }
    #pragma unroll
    for (int c2 = 0; c2 < 8; ++c2){
      uint4 wv0 = *(const uint4*)&wlds[tid*64      + (((unsigned)c2 ^ swz)*4)];
      uint4 wv1 = *(const uint4*)&wlds[tid*64 + 32 + (((unsigned)c2 ^ swz)*4)];
      uint4 h4 = hp[24 + c2];
      acc0 = fdot2u(wv0.x, h4.x, acc0);
      acc0 = fdot2u(wv0.y, h4.y, acc0);
      acc0 = fdot2u(wv0.z, h4.z, acc0);
      acc0 = fdot2u(wv0.w, h4.w, acc0);
      acc1 = fdot2u(wv1.x, h4.x, acc1);
      acc1 = fdot2u(wv1.y, h4.y, acc1);
      acc1 = fdot2u(wv1.z, h4.z, acc1);
      acc1 = fdot2u(wv1.w, h4.w, acc1);
    }
    h2 gp = __builtin_bit_cast(h2, gc);
    gf[r0] = acc0 + (float)gp[0];
    gf[r1] = acc1 + (float)gp[1];
    __syncthreads();
    if (tid < 256){
      float gi = gf[tid], gfr = gf[tid + 256], gg = gf[tid + 512], go = gf[tid + 768];
      float ct = sigmf(gfr)*c_reg + sigmf(gi)*tanhf_(gg);
      c_reg = ct;
      hn = sigmf(go)*tanhf_(ct);
      ((_Float16*)h_pk_s)[tid] = (_Float16)hn;
      hout[(size_t)tl*256 + tid] = (_Float16)hn;
    }
    __syncthreads();
    gc = gn;
  }
  if (tid < 256){ h_state[b*256 + tid] = hn; c_state[b*256 + tid] = c_reg; }
}

// --------------------------- LayerNorm + 9-head scores + gather ------------
__global__ void k_ln(const _Float16* __restrict__ H1, const float* __restrict__ vk,
                     const float* __restrict__ ck, const int* __restrict__ idx,
                     float* __restrict__ out, int Tc, int LT, int tc0)
{
  __shared__ __align__(16) float vks[9*256];
  __shared__ float cks[9];
  int tid = threadIdx.x;
  for (int i = tid; i < 2304; i += 256) vks[i] = vk[i];
  if (tid < 9) cks[tid] = ck[tid];
  __syncthreads();
  int l = tid & 63, wv = tid >> 6;
  int m = blockIdx.x*4 + wv;
  int b = m >> LT; int t = tc0 + (m & (Tc-1));
  uint2 hv = *(const uint2*)(H1 + (size_t)m*256 + l*4);
  h2 pa = __builtin_bit_cast(h2, hv.x), pb = __builtin_bit_cast(h2, hv.y);
  float f0 = pa[0], f1 = pa[1], f2 = pb[0], f3 = pb[1];
  float s = f0 + f1 + f2 + f3;
  float q = f0*f0 + f1*f1 + f2*f2 + f3*f3;
  #pragma unroll
  for (int o = 32; o > 0; o >>= 1){ s += __shfl_xor(s, o, 64); q += __shfl_xor(q, o, 64); }
  float mu = s*(1.f/256.f);
  float var = q*(1.f/256.f) - mu*mu;
  float rstd = rsqrtf(var + 1e-5f);
  float xh0 = (f0 - mu)*rstd, xh1 = (f1 - mu)*rstd, xh2 = (f2 - mu)*rstd, xh3 = (f3 - mu)*rstd;
  int ib = idx[b];
  size_t rout = (size_t)b*1024 + t;
  #pragma unroll 1
  for (int k = 0; k < 9; ++k){
    float4 vvv = *(const float4*)(vks + k*256 + l*4);
    float p = xh0*vvv.x + xh1*vvv.y + xh2*vvv.z + xh3*vvv.w;
    #pragma unroll
    for (int o = 32; o > 0; o >>= 1) p += __shfl_xor(p, o, 64);
    if (l == 0){
      float sc = p + cks[k];
      if (k < 4) out[640 + (size_t)k*131072 + rout] = sc;
      else if (t == ib) out[(k - 4)*128 + b] = sc;
    }
  }
}

// --------------------------- host launcher ---------------------------------
extern "C" void kernel_launch(void* const* d_in, const int* in_sizes, int n_in,
                              void* d_out, int out_size, void* d_ws, size_t ws_size,
                              hipStream_t stream)
{
  const float* x      = (const float*)d_in[0];
  const int*   phn    = (const int*)  d_in[1];
  const float* in_w   = (const float*)d_in[2];
  const float* in_b   = (const float*)d_in[3];
  const float* ph_w   = (const float*)d_in[4];
  const float* ph_b   = (const float*)d_in[5];
  const float* w_ih   = (const float*)d_in[6];
  const float* w_hh   = (const float*)d_in[7];
  const float* b_ih   = (const float*)d_in[8];
  const float* b_hh   = (const float*)d_in[9];
  const float* ln_g   = (const float*)d_in[10];
  const float* ln_b   = (const float*)d_in[11];
  const float* head_w = (const float*)d_in[12];
  const float* head_b = (const float*)d_in[13];
  float* out = (float*)d_out;
  char* wsb = (char*)d_ws;
  size_t o = 0;
  auto take = [&](size_t n) -> char* { char* p = wsb + o; o = (o + n + 255) & ~(size_t)255; return p; };
  _Float16* wih0 = (_Float16*)take(524288);
  _Float16* whh0 = (_Float16*)take(524288);
  _Float16* wih1 = (_Float16*)take(524288);
  _Float16* whh1 = (_Float16*)take(524288);
  float* bias0 = (float*)take(4096);
  float* bias1 = (float*)take(4096);
  float* vk    = (float*)take(9216);
  float* ck    = (float*)take(64);
  int*   idxb  = (int*)take(512);
  float* h0s = (float*)take(131072);
  float* c0s = (float*)take(131072);
  float* h1s = (float*)take(131072);
  float* c1s = (float*)take(131072);
  const size_t per_t = 3*(size_t)65536 + 1048576;   // E + H0 + H1 + G per timestep
  int Tc = 1024;
  while (Tc > 8 && o + (size_t)Tc*per_t > ws_size) Tc >>= 1;
  _Float16* Eb  = (_Float16*)take((size_t)Tc*65536);
  _Float16* H0b = (_Float16*)take((size_t)Tc*65536);
  _Float16* H1b = (_Float16*)take((size_t)Tc*65536);
  _Float16* Gb  = (_Float16*)take((size_t)Tc*1048576);
  int LT = __builtin_ctz((unsigned)Tc);

  k_prep<<<1024, 256, 0, stream>>>(w_ih, w_hh, b_ih, b_hh, ln_g, ln_b, head_w, head_b,
                                   wih0, whh0, wih1, whh1, bias0, bias1, vk, ck);
  k_idx<<<128, 64, 0, stream>>>(phn, idxb);

  int M = 128*Tc;
  int nchunks = 1024/Tc;
  for (int c = 0; c < nchunks; ++c){
    int tc0 = c*Tc;
    k_embed<<<M/8, 256, 0, stream>>>(x, phn, in_w, in_b, ph_w, ph_b, Eb, Tc, LT, tc0);
    k_gemm<<<dim3(M/128, 8), 256, 0, stream>>>(Eb, wih0, bias0, Gb);
    k_lstm<<<128, 512, 0, stream>>>(Gb, whh0, H0b, h0s, c0s, Tc, c == 0 ? 1 : 0);
    k_gemm<<<dim3(M/128, 8), 256, 0, stream>>>(H0b, wih1, bias1, Gb);
    k_lstm<<<128, 512, 0, stream>>>(Gb, whh1, H1b, h1s, c1s, Tc, c == 0 ? 1 : 0);
    k_ln<<<M/4, 256, 0, stream>>>(H1b, vk, ck, idxb, out, Tc, LT, tc0);
  }
  (void)in_sizes; (void)n_in; (void)out_size;
}